// Round 1
// baseline (453.747 us; speedup 1.0000x reference)
//
#include <hip/hip_runtime.h>

// out = A @ W @ B, A/B block-diagonal with 128 blocks of 64x64.
// One workgroup (256 thr) per (a,b) block pair: out_ab = A_a * W_ab * B_b.
// Memory-bound: W read (256 MiB) + out write (256 MiB) dominate; compute done
// in bf16 MFMA 16x16x32 (fp32 accumulate) so MFMA time ~8us << HBM ~85us.

#define D 8192
#define BS 64
#define LSTR 72   // LDS row stride in bf16 elems: 144 B = 16B-aligned, staggers banks

typedef __bf16 bf16x8 __attribute__((ext_vector_type(8)));
typedef float  f32x4  __attribute__((ext_vector_type(4)));

__device__ __forceinline__ unsigned short f2bf(float f) {
    // round-to-nearest-even fp32 -> bf16 (no NaN handling needed: inputs are finite)
    union { float f; unsigned u; } v; v.f = f;
    unsigned r = v.u + 0x7FFFu + ((v.u >> 16) & 1u);
    return (unsigned short)(r >> 16);
}

__global__ __launch_bounds__(256, 4) void bcl_kernel(
    const float* __restrict__ W,
    const float* __restrict__ Ab,
    const float* __restrict__ Bb,
    float* __restrict__ out)
{
    __shared__ __align__(16) unsigned short Wl[BS * LSTR]; // W_ab row-major [m][k]
    __shared__ __align__(16) unsigned short Al[BS * LSTR]; // A_a  row-major [m][k]
    __shared__ __align__(16) unsigned short Bt[BS * LSTR]; // B_b transposed [n][k]
    __shared__ __align__(16) unsigned short Tt[BS * LSTR]; // tmp transposed [n][k]

    const int t = threadIdx.x;
    const int b = blockIdx.x;   // input-side (column) block
    const int a = blockIdx.y;   // output-side (row) block

    const float* Wg = W  + (size_t)a * BS * D + (size_t)b * BS;
    const float* Ag = Ab + (size_t)a * BS * BS;
    const float* Bg = Bb + (size_t)b * BS * BS;

    // ---- stage: 64x64 fp32 -> bf16 LDS. Coalesced float4 global reads. ----
    #pragma unroll
    for (int i = 0; i < 4; ++i) {
        int lin = i * 256 + t;        // 0..1023
        int row = lin >> 4;           // 0..63
        int c4  = (lin & 15) << 2;    // 0,4,...,60
        f32x4 w  = *(const f32x4*)(Wg + (size_t)row * D + c4);
        f32x4 av = *(const f32x4*)(Ag + row * BS + c4);
        f32x4 bv = *(const f32x4*)(Bg + row * BS + c4);
        uint2 wp, ap;
        wp.x = (unsigned)f2bf(w[0])  | ((unsigned)f2bf(w[1])  << 16);
        wp.y = (unsigned)f2bf(w[2])  | ((unsigned)f2bf(w[3])  << 16);
        ap.x = (unsigned)f2bf(av[0]) | ((unsigned)f2bf(av[1]) << 16);
        ap.y = (unsigned)f2bf(av[2]) | ((unsigned)f2bf(av[3]) << 16);
        *(uint2*)&Wl[row * LSTR + c4] = wp;   // 8B aligned: 144*row + 2*c4
        *(uint2*)&Al[row * LSTR + c4] = ap;
        // B transposed: Bt[n][k] = B[k][n]; row here is k
        Bt[(c4 + 0) * LSTR + row] = f2bf(bv[0]);
        Bt[(c4 + 1) * LSTR + row] = f2bf(bv[1]);
        Bt[(c4 + 2) * LSTR + row] = f2bf(bv[2]);
        Bt[(c4 + 3) * LSTR + row] = f2bf(bv[3]);
    }
    __syncthreads();

    const int lane = t & 63;
    const int wv   = t >> 6;        // wave 0..3
    const int l16  = lane & 15;
    const int quad = lane >> 4;
    const int m0   = wv * 16;       // this wave owns rows m0..m0+15, all 64 cols

    // ---- matmul 1: tmp = W_ab @ B_b  (A-op = Wl row-major, B-op = Bt [n][k]) ----
    f32x4 acc[4] = {};
    #pragma unroll
    for (int s = 0; s < 2; ++s) {
        const int k0 = s * 32 + quad * 8;
        bf16x8 af = *(const bf16x8*)&Wl[(m0 + l16) * LSTR + k0];
        #pragma unroll
        for (int j = 0; j < 4; ++j) {
            bf16x8 bf = *(const bf16x8*)&Bt[(j * 16 + l16) * LSTR + k0];
            acc[j] = __builtin_amdgcn_mfma_f32_16x16x32_bf16(af, bf, acc[j], 0, 0, 0);
        }
    }

    // C/D layout: lane holds tmp[m0 + quad*4 + r][j*16 + l16], r=0..3.
    // Store transposed (Tt[col][row]) so matmul-2 B-frags are contiguous-k.
    #pragma unroll
    for (int j = 0; j < 4; ++j) {
        uint2 p;
        p.x = (unsigned)f2bf(acc[j][0]) | ((unsigned)f2bf(acc[j][1]) << 16);
        p.y = (unsigned)f2bf(acc[j][2]) | ((unsigned)f2bf(acc[j][3]) << 16);
        *(uint2*)&Tt[(j * 16 + l16) * LSTR + m0 + quad * 4] = p;
    }
    __syncthreads();

    // ---- matmul 2: out_ab = A_a @ tmp  (A-op = Al row-major, B-op = Tt [n][k]) ----
    f32x4 acc2[4] = {};
    #pragma unroll
    for (int s = 0; s < 2; ++s) {
        const int k0 = s * 32 + quad * 8;
        bf16x8 af = *(const bf16x8*)&Al[(m0 + l16) * LSTR + k0];
        #pragma unroll
        for (int j = 0; j < 4; ++j) {
            bf16x8 bf = *(const bf16x8*)&Tt[(j * 16 + l16) * LSTR + k0];
            acc2[j] = __builtin_amdgcn_mfma_f32_16x16x32_bf16(af, bf, acc2[j], 0, 0, 0);
        }
    }

    // ---- store fp32: each quad writes 64B contiguous per row ----
    float* Og = out + (size_t)a * BS * D + (size_t)b * BS;
    #pragma unroll
    for (int j = 0; j < 4; ++j) {
        #pragma unroll
        for (int r = 0; r < 4; ++r) {
            Og[(size_t)(m0 + quad * 4 + r) * D + j * 16 + l16] = acc2[j][r];
        }
    }
}

extern "C" void kernel_launch(void* const* d_in, const int* in_sizes, int n_in,
                              void* d_out, int out_size, void* d_ws, size_t ws_size,
                              hipStream_t stream) {
    const float* W = (const float*)d_in[0];
    const float* A = (const float*)d_in[1];
    const float* B = (const float*)d_in[2];
    float* o = (float*)d_out;
    dim3 grid(D / BS, D / BS);  // x = b (col block), y = a (row block)
    bcl_kernel<<<grid, 256, 0, stream>>>(W, A, B, o);
}

// Round 2
// 434.852 us; speedup vs baseline: 1.0435x; 1.0435x over previous
//
#include <hip/hip_runtime.h>
#include <hip/hip_bf16.h>

// out = A @ W @ B, A/B block-diagonal with 128 blocks of 64x64.
// One workgroup (256 thr) per (a,b) pair: out_ab = A_a * W_ab * B_b.
// bf16 MFMA 16x16x32, fp32 accumulate. Memory-bound on W read + out write.
// R2 changes: (1) all 12 global loads issued up front, A-convert deferred to
// overlap mm1; (2) out tile staged in LDS -> float4 coalesced stores;
// (3) nontemporal W loads / out stores to keep A/B L2-resident.

#define D 8192
#define BS 64
#define LSTR 72   // bf16 LDS row stride (144 B: 16B-aligned, bank-staggered)
#define OSTR 68   // fp32 out-staging row stride (272 B: 16B-aligned, 2-way max)

typedef __bf16  bf16x8 __attribute__((ext_vector_type(8)));
typedef float   f32x4  __attribute__((ext_vector_type(4)));

__device__ __forceinline__ unsigned short f2bf(float f) {
    union { float f; unsigned u; } v; v.f = f;
    unsigned r = v.u + 0x7FFFu + ((v.u >> 16) & 1u);
    return (unsigned short)(r >> 16);
}

__device__ __forceinline__ unsigned pkbf(float lo, float hi) {
    // packed RNE f32->bf16 pair; header helper maps to HW packed cvt if present
    union { __hip_bfloat162 h; unsigned u; } c;
    c.h = __float22bfloat162_rn(make_float2(lo, hi));
    return c.u;
}

__global__ __launch_bounds__(256, 4) void bcl_kernel(
    const float* __restrict__ W,
    const float* __restrict__ Ab,
    const float* __restrict__ Bb,
    float* __restrict__ out)
{
    __shared__ __align__(16) unsigned char smem[36864];
    unsigned short* Wl = (unsigned short*)(smem);           // [64][72] W_ab row-major
    unsigned short* Al = (unsigned short*)(smem + 9216);    // [64][72] A_a row-major
    unsigned short* Bt = (unsigned short*)(smem + 18432);   // [64][72] B_b transposed [n][k]
    unsigned short* Tt = (unsigned short*)(smem + 27648);   // [64][72] tmp transposed [n][k]
    float*          Ol = (float*)(smem);                    // [64][68] out staging (17408 B, overlaps Wl+Al)

    const int t = threadIdx.x;
    const int b = blockIdx.x;   // input-side (column) block
    const int a = blockIdx.y;   // output-side (row) block

    const float* Wg = W  + (size_t)a * BS * D + (size_t)b * BS;
    const float* Ag = Ab + (size_t)a * BS * BS;
    const float* Bg = Bb + (size_t)b * BS * BS;

    const int r0 = t >> 4;          // 0..15
    const int c4 = (t & 15) << 2;   // 0,4,...,60

    // ---- issue ALL global loads up front (48 data VGPRs, fits 128 cap) ----
    f32x4 w[4], av[4], bv[4];
    #pragma unroll
    for (int i = 0; i < 4; ++i) {
        const int row = i * 16 + r0;
        w[i]  = __builtin_nontemporal_load((const f32x4*)(Wg + (size_t)row * D + c4));
        av[i] = *(const f32x4*)(Ag + row * BS + c4);
        bv[i] = *(const f32x4*)(Bg + row * BS + c4);
    }

    // ---- convert + stage W (row-major) and B (transposed) only; A deferred ----
    #pragma unroll
    for (int i = 0; i < 4; ++i) {
        const int row = i * 16 + r0;   // for B this is k
        uint2 wp;
        wp.x = pkbf(w[i][0], w[i][1]);
        wp.y = pkbf(w[i][2], w[i][3]);
        *(uint2*)&Wl[row * LSTR + c4] = wp;
        Bt[(c4 + 0) * LSTR + row] = f2bf(bv[i][0]);
        Bt[(c4 + 1) * LSTR + row] = f2bf(bv[i][1]);
        Bt[(c4 + 2) * LSTR + row] = f2bf(bv[i][2]);
        Bt[(c4 + 3) * LSTR + row] = f2bf(bv[i][3]);
    }
    __syncthreads();

    const int lane = t & 63;
    const int wv   = t >> 6;
    const int l16  = lane & 15;
    const int quad = lane >> 4;
    const int m0   = wv * 16;       // wave owns rows m0..m0+15, all 64 cols

    // ---- matmul 1: tmp = W_ab @ B_b ----
    f32x4 acc[4] = {};
    #pragma unroll
    for (int s = 0; s < 2; ++s) {
        const int k0 = s * 32 + quad * 8;
        bf16x8 af = *(const bf16x8*)&Wl[(m0 + l16) * LSTR + k0];
        #pragma unroll
        for (int j = 0; j < 4; ++j) {
            bf16x8 bf = *(const bf16x8*)&Bt[(j * 16 + l16) * LSTR + k0];
            acc[j] = __builtin_amdgcn_mfma_f32_16x16x32_bf16(af, bf, acc[j], 0, 0, 0);
        }
    }

    // ---- stage A (overlaps mm1 MFMA latency) ----
    #pragma unroll
    for (int i = 0; i < 4; ++i) {
        const int row = i * 16 + r0;
        uint2 ap;
        ap.x = pkbf(av[i][0], av[i][1]);
        ap.y = pkbf(av[i][2], av[i][3]);
        *(uint2*)&Al[row * LSTR + c4] = ap;
    }

    // C/D: lane holds tmp[m0+quad*4+r][j*16+l16]; store transposed Tt[col][row]
    #pragma unroll
    for (int j = 0; j < 4; ++j) {
        uint2 p;
        p.x = pkbf(acc[j][0], acc[j][1]);
        p.y = pkbf(acc[j][2], acc[j][3]);
        *(uint2*)&Tt[(j * 16 + l16) * LSTR + m0 + quad * 4] = p;
    }
    __syncthreads();

    // ---- matmul 2: out_ab = A_a @ tmp ----
    f32x4 acc2[4] = {};
    #pragma unroll
    for (int s = 0; s < 2; ++s) {
        const int k0 = s * 32 + quad * 8;
        bf16x8 af = *(const bf16x8*)&Al[(m0 + l16) * LSTR + k0];
        #pragma unroll
        for (int j = 0; j < 4; ++j) {
            bf16x8 bf = *(const bf16x8*)&Tt[(j * 16 + l16) * LSTR + k0];
            acc2[j] = __builtin_amdgcn_mfma_f32_16x16x32_bf16(af, bf, acc2[j], 0, 0, 0);
        }
    }
    __syncthreads();   // Al/Tt reads done; Ol may now overwrite Wl/Al region

    // ---- stage out tile fp32 in LDS (OSTR=68 -> <=2-way bank conflicts) ----
    #pragma unroll
    for (int j = 0; j < 4; ++j) {
        #pragma unroll
        for (int r = 0; r < 4; ++r) {
            Ol[(m0 + quad * 4 + r) * OSTR + j * 16 + l16] = acc2[j][r];
        }
    }
    __syncthreads();

    // ---- coalesced float4 stores: wave instr covers 4 rows x 256 B ----
    float* Og = out + (size_t)a * BS * D + (size_t)b * BS;
    #pragma unroll
    for (int i = 0; i < 4; ++i) {
        const int row = i * 16 + r0;
        f32x4 v = *(const f32x4*)&Ol[row * OSTR + c4];
        __builtin_nontemporal_store(v, (f32x4*)(Og + (size_t)row * D + c4));
    }
}

extern "C" void kernel_launch(void* const* d_in, const int* in_sizes, int n_in,
                              void* d_out, int out_size, void* d_ws, size_t ws_size,
                              hipStream_t stream) {
    const float* W = (const float*)d_in[0];
    const float* A = (const float*)d_in[1];
    const float* B = (const float*)d_in[2];
    float* o = (float*)d_out;
    dim3 grid(D / BS, D / BS);  // x = b (col block), y = a (row block)
    bcl_kernel<<<grid, 256, 0, stream>>>(W, A, B, o);
}